// Round 2
// baseline (8414.558 us; speedup 1.0000x reference)
//
#include <hip/hip_runtime.h>
#include <hip/hip_bf16.h>

// PathRNN: h_{t+1} = tanh(x_t + W_hh h_t), u = h, pos = u @ W_out^T
// B=128, T=1024, H=512.
// Decomposition: 8 cohorts (16 batches) x 8 N-slices (64 cols) = 64 wave-tasks.
// Grid: 16 WGs x 128 thr; wave w of WG (i = bid&7, half = bid>>3) owns slice i
// and cohorts {half*4 + w*2, +1}. No intra-WG sync. W slice in regs (AGPR),
// h per cohort in private swizzled 16KB LDS slot. Exchange via wide (8B)
// agent-scope atomics through L3, latency hidden by 2-cohort interleave.

#define TT 1024
#define BB 128
#define HH 512

typedef short s16x8 __attribute__((ext_vector_type(8)));
typedef float f32x4 __attribute__((ext_vector_type(4)));
typedef unsigned int uint;
typedef unsigned short ushort_t;
typedef unsigned long long u64;

#define MFMA_B16(a, b, c) __builtin_amdgcn_mfma_f32_16x16x32_bf16((a), (b), (c), 0, 0, 0)

__device__ __forceinline__ ushort_t bf16_rne(float f) {
  uint u = __float_as_uint(f);
  u += 0x7fffu + ((u >> 16) & 1u);
  return (ushort_t)(u >> 16);
}

__device__ __forceinline__ float tanh_fast(float z) {
  float e = __expf(2.0f * z);
  return 1.0f - 2.0f * __builtin_amdgcn_rcpf(e + 1.0f);
}

// ---- per-cohort phase macros (instantiated twice, static unroll only) ----

#define COMPUTE_STEP(cc, slotbase, acc, vv)                                      \
  {                                                                              \
    _Pragma("unroll") for (int r = 0; r < 4; ++r)                                \
        vv[r] = *(const float2*)(vel + ((size_t)((cc)*16 + kg*4 + r)*TT + t)*2); \
    _Pragma("unroll") for (int kt = 0; kt < 16; ++kt) {                          \
      uint logical = (uint)l15*1024u + (uint)kt*64u + (uint)kg*16u;              \
      s16x8 a = *(const s16x8*)(hlds + (slotbase) +                              \
                                (logical ^ (((uint)l15 & 7u) << 4)));            \
      acc[0] = MFMA_B16(a, wreg[0][kt], acc[0]);                                 \
      acc[1] = MFMA_B16(a, wreg[1][kt], acc[1]);                                 \
      acc[2] = MFMA_B16(a, wreg[2][kt], acc[2]);                                 \
      acc[3] = MFMA_B16(a, wreg[3][kt], acc[3]);                                 \
    }                                                                            \
  }

#define EPILOGUE_STEP(cc, slotbase, acc, vv)                                     \
  {                                                                              \
    _Pragma("unroll") for (int r = 0; r < 4; ++r) {                              \
      int bl = kg*4 + r;                                                         \
      size_t ubase = ((size_t)((cc)*16 + bl)*TT + t)*HH;                         \
      uint swz = ((uint)bl & 7u) << 4;                                           \
      _Pragma("unroll") for (int nt = 0; nt < 4; ++nt) {                         \
        float x = fmaf(vv[r].x, wihA[nt], fmaf(vv[r].y, wihB[nt], bsv[nt]));     \
        float uval = tanh_fast(x + acc[nt][r]);                                  \
        __builtin_nontemporal_store(uval, u_out + ubase + n0 + nt*16 + l15);     \
        uint logical = (uint)bl*1024u + (uint)(n0 + nt*16 + l15)*2u;             \
        *(ushort_t*)(hlds + (slotbase) + (logical ^ swz)) = bf16_rne(uval);      \
      }                                                                          \
    }                                                                            \
  }

#define PUBLISH_STEP(cc, slotbase, par)                                          \
  {                                                                              \
    uint row = (uint)lane >> 2, cb = (uint)lane & 3u;                            \
    uint logical = row*1024u + (uint)n0*2u + cb*32u;                             \
    uint phys = (uint)(slotbase) + (logical ^ ((row & 7u) << 4));                \
    uint4 d0 = *(const uint4*)(hlds + phys);                                     \
    uint4 d1 = *(const uint4*)(hlds + (phys ^ 16u));                             \
    u64* dst = pub + (((size_t)(par)*8 + (cc))*8 + i)*256 + (uint)lane*4;        \
    __hip_atomic_store(dst+0, (u64)d0.x | ((u64)d0.y << 32), __ATOMIC_RELAXED, __HIP_MEMORY_SCOPE_AGENT); \
    __hip_atomic_store(dst+1, (u64)d0.z | ((u64)d0.w << 32), __ATOMIC_RELAXED, __HIP_MEMORY_SCOPE_AGENT); \
    __hip_atomic_store(dst+2, (u64)d1.x | ((u64)d1.y << 32), __ATOMIC_RELAXED, __HIP_MEMORY_SCOPE_AGENT); \
    __hip_atomic_store(dst+3, (u64)d1.z | ((u64)d1.w << 32), __ATOMIC_RELAXED, __HIP_MEMORY_SCOPE_AGENT); \
  }

#define SPIN_STEP(cc, tgt)                                                       \
  {                                                                              \
    int jj = lane + (lane >= i ? 1 : 0);                                         \
    while (true) {                                                               \
      uint f = (lane < 7) ? __hip_atomic_load(&flags[(cc)*8 + jj],               \
                   __ATOMIC_RELAXED, __HIP_MEMORY_SCOPE_AGENT) : 0xFFFFFFFFu;    \
      if (__all((int)(f >= (uint)(tgt)))) break;                                 \
    }                                                                            \
    asm volatile("" ::: "memory");                                               \
  }

#define GATHER_ISSUE(cc, par, g)                                                 \
  {                                                                              \
    _Pragma("unroll") for (int s7 = 0; s7 < 7; ++s7) {                           \
      int j = s7 + (s7 >= i ? 1 : 0);                                            \
      const u64* src = pub + (((size_t)(par)*8 + (cc))*8 + j)*256 + (uint)lane*4;\
      _Pragma("unroll") for (int q = 0; q < 4; ++q)                              \
        g[s7*4 + q] = __hip_atomic_load(src + q, __ATOMIC_RELAXED,               \
                                        __HIP_MEMORY_SCOPE_AGENT);               \
    }                                                                            \
  }

#define GATHER_WRITE(cc, slotbase, g)                                            \
  {                                                                              \
    uint row = (uint)lane >> 2, cb = (uint)lane & 3u;                            \
    uint swz = (row & 7u) << 4;                                                  \
    _Pragma("unroll") for (int s7 = 0; s7 < 7; ++s7) {                           \
      int j = s7 + (s7 >= i ? 1 : 0);                                            \
      uint logical = row*1024u + (uint)j*128u + cb*32u;                          \
      uint phys = (uint)(slotbase) + (logical ^ swz);                            \
      uint4 u01, u23;                                                            \
      u01.x = (uint)g[s7*4+0]; u01.y = (uint)(g[s7*4+0] >> 32);                  \
      u01.z = (uint)g[s7*4+1]; u01.w = (uint)(g[s7*4+1] >> 32);                  \
      u23.x = (uint)g[s7*4+2]; u23.y = (uint)(g[s7*4+2] >> 32);                  \
      u23.z = (uint)g[s7*4+3]; u23.w = (uint)(g[s7*4+3] >> 32);                  \
      *(uint4*)(hlds + phys) = u01;                                              \
      *(uint4*)(hlds + (phys ^ 16u)) = u23;                                      \
    }                                                                            \
  }

__global__ __launch_bounds__(128, 1) void rnn_kernel(
    const float* __restrict__ vel, const float* __restrict__ W_ih,
    const float* __restrict__ W_hh, const float* __restrict__ b_ih,
    const float* __restrict__ b_hh, float* __restrict__ u_out,
    uint* __restrict__ flags, u64* __restrict__ pub) {
  __shared__ uint4 hlds_mem[4096];  // 64 KiB = 4 slots x 16 KiB
  char* hlds = (char*)hlds_mem;

  const int tid = threadIdx.x;
  const int lane = tid & 63;
  const int w = tid >> 6;      // wave 0..1
  const int bid = blockIdx.x;
  const int i = bid & 7;       // N-slice 0..7
  const int chalf = bid >> 3;  // 0..1
  const int cA = chalf*4 + w*2;
  const int cB = cA + 1;
  const int l15 = lane & 15;
  const int kg = lane >> 4;
  const int n0 = i * 64;
  const int slotA = (w*2 + 0) * 16384;
  const int slotB = (w*2 + 1) * 16384;

  // ---- one-time: W slice (64 cols x 512 K) -> regs as bf16 B-frags ----
  s16x8 wreg[4][16];
#pragma unroll
  for (int nt = 0; nt < 4; ++nt)
#pragma unroll
    for (int kt = 0; kt < 16; ++kt) {
      const float* wp = W_hh + (size_t)(n0 + nt*16 + l15)*HH + kt*32 + kg*8;
      float4 lo = *(const float4*)wp;
      float4 hi = *(const float4*)(wp + 4);
      s16x8 s;
      s[0] = (short)bf16_rne(lo.x); s[1] = (short)bf16_rne(lo.y);
      s[2] = (short)bf16_rne(lo.z); s[3] = (short)bf16_rne(lo.w);
      s[4] = (short)bf16_rne(hi.x); s[5] = (short)bf16_rne(hi.y);
      s[6] = (short)bf16_rne(hi.z); s[7] = (short)bf16_rne(hi.w);
      wreg[nt][kt] = s;
    }
  float wihA[4], wihB[4], bsv[4];
#pragma unroll
  for (int nt = 0; nt < 4; ++nt) {
    int n = n0 + nt*16 + l15;
    wihA[nt] = W_ih[n*2 + 0];
    wihB[nt] = W_ih[n*2 + 1];
    bsv[nt] = b_ih[n] + b_hh[n];
  }

  // ---- zero own two h slots (h_0 = 0); no barrier needed (wave-private) ----
  {
    uint4 z = {0u, 0u, 0u, 0u};
#pragma unroll
    for (int q = 0; q < 16; ++q) {
      *(uint4*)(hlds + slotA + lane*16 + q*1024) = z;
      *(uint4*)(hlds + slotB + lane*16 + q*1024) = z;
    }
  }

  const f32x4 z4 = {0.f, 0.f, 0.f, 0.f};
  for (int t = 0; t < TT; ++t) {
    const int par = (t + 1) & 1;
    f32x4 accA[4] = {z4, z4, z4, z4};
    f32x4 accB[4] = {z4, z4, z4, z4};
    float2 vA[4], vB[4];

    COMPUTE_STEP(cA, slotA, accA, vA);
    EPILOGUE_STEP(cA, slotA, accA, vA);
    PUBLISH_STEP(cA, slotA, par);

    COMPUTE_STEP(cB, slotB, accB, vB);
    EPILOGUE_STEP(cB, slotB, accB, vB);
    PUBLISH_STEP(cB, slotB, par);

    if (t == TT - 1) break;

    // release: all publish stores visible at L3 before flags
    asm volatile("s_waitcnt vmcnt(0)" ::: "memory");
    __hip_atomic_store(&flags[cA*8 + i], (uint)(t + 1), __ATOMIC_RELAXED,
                       __HIP_MEMORY_SCOPE_AGENT);
    __hip_atomic_store(&flags[cB*8 + i], (uint)(t + 1), __ATOMIC_RELAXED,
                       __HIP_MEMORY_SCOPE_AGENT);

    u64 gA[28], gB[28];
    SPIN_STEP(cA, t + 1);
    GATHER_ISSUE(cA, par, gA);
    SPIN_STEP(cB, t + 1);
    GATHER_ISSUE(cB, par, gB);
    // compiler inserts vmcnt waits on g-register use; in-order returns mean
    // gA completes while gB is still in flight.
    GATHER_WRITE(cA, slotA, gA);
    GATHER_WRITE(cB, slotB, gB);
  }
}

__global__ void init_kernel(uint* flags) {
  __hip_atomic_store(&flags[threadIdx.x], 0u, __ATOMIC_RELAXED, __HIP_MEMORY_SCOPE_AGENT);
}

// pos[b,t,:] = u[b,t,:] @ W_out^T + b_out ; one wave per (b,t) row, BW-bound.
__global__ __launch_bounds__(256) void pos_kernel(const float* __restrict__ u,
                                                  const float* __restrict__ W_out,
                                                  const float* __restrict__ b_out,
                                                  float* __restrict__ pos) {
  int row = blockIdx.x * 4 + (threadIdx.x >> 6);
  int lane = threadIdx.x & 63;
  const float* ur = u + (size_t)row * HH + lane * 8;
  float4 u0 = *(const float4*)ur;
  float4 u1 = *(const float4*)(ur + 4);
  float4 w00 = *(const float4*)(W_out + lane * 8);
  float4 w01 = *(const float4*)(W_out + lane * 8 + 4);
  float4 w10 = *(const float4*)(W_out + HH + lane * 8);
  float4 w11 = *(const float4*)(W_out + HH + lane * 8 + 4);
  float p0 = u0.x * w00.x + u0.y * w00.y + u0.z * w00.z + u0.w * w00.w +
             u1.x * w01.x + u1.y * w01.y + u1.z * w01.z + u1.w * w01.w;
  float p1 = u0.x * w10.x + u0.y * w10.y + u0.z * w10.z + u0.w * w10.w +
             u1.x * w11.x + u1.y * w11.y + u1.z * w11.z + u1.w * w11.w;
#pragma unroll
  for (int off = 32; off; off >>= 1) {
    p0 += __shfl_xor(p0, off);
    p1 += __shfl_xor(p1, off);
  }
  if (lane == 0) {
    pos[(size_t)row * 2 + 0] = p0 + b_out[0];
    pos[(size_t)row * 2 + 1] = p1 + b_out[1];
  }
}

extern "C" void kernel_launch(void* const* d_in, const int* in_sizes, int n_in,
                              void* d_out, int out_size, void* d_ws, size_t ws_size,
                              hipStream_t stream) {
  const float* vel   = (const float*)d_in[0];
  const float* W_ih  = (const float*)d_in[1];
  const float* W_hh  = (const float*)d_in[2];
  const float* b_ih  = (const float*)d_in[3];
  const float* b_hh  = (const float*)d_in[4];
  const float* W_out = (const float*)d_in[5];
  const float* b_out = (const float*)d_in[6];

  float* pos = (float*)d_out;              // [B,T,2]
  float* u   = pos + (size_t)BB * TT * 2;  // [B,T,H]

  // workspace: flags (64 x u32 at offset 0) + pub (2 par x 8 c x 8 i x 2 KiB)
  uint* flags = (uint*)d_ws;
  u64* pub = (u64*)((char*)d_ws + 4096);

  init_kernel<<<1, 64, 0, stream>>>(flags);
  rnn_kernel<<<16, 128, 0, stream>>>(vel, W_ih, W_hh, b_ih, b_hh, u, flags, pub);
  pos_kernel<<<(BB * TT) / 4, 256, 0, stream>>>(u, W_out, b_out, pos);
}

// Round 3
// 2254.655 us; speedup vs baseline: 3.7321x; 3.7321x over previous
//
#include <hip/hip_runtime.h>
#include <hip/hip_bf16.h>

// PathRNN: h_{t+1} = tanh(x_t + W_hh h_t), u = h, pos = u @ W_out^T
// B=128, T=1024, H=512.
// 64 WGs = 8 cohorts (16 batches) x 8 N-slices (64 cols); 4 waves/WG, 16 cols/wave.
// W in regs (64 VGPR/lane). h in 2x16KB swizzled LDS. Per step: MFMA -> tanh ->
// publish own 16x64 slice straight from regs (col-major pub, 1 u64/lane,
// agent-scope relaxed atomics through L3, NO fences - vmcnt discipline only)
// -> per-wave flag -> spin on 28 peer flags -> gather 7 u64/lane -> LDS.
// One __syncthreads per step.

#define TT 1024
#define BB 128
#define HH 512

typedef short s16x8 __attribute__((ext_vector_type(8)));
typedef float f32x4 __attribute__((ext_vector_type(4)));
typedef unsigned int uint;
typedef unsigned short ushort_t;
typedef unsigned long long u64;

#define MFMA_B16(a, b, c) __builtin_amdgcn_mfma_f32_16x16x32_bf16((a), (b), (c), 0, 0, 0)

__device__ __forceinline__ ushort_t bf16_rne(float f) {
  uint u = __float_as_uint(f);
  u += 0x7fffu + ((u >> 16) & 1u);
  return (ushort_t)(u >> 16);
}

__device__ __forceinline__ float tanh_fast(float z) {
  float e = __expf(2.0f * z);
  return 1.0f - 2.0f * __builtin_amdgcn_rcpf(e + 1.0f);
}

__global__ __launch_bounds__(256) void rnn_kernel(
    const float* __restrict__ vel, const float* __restrict__ W_ih,
    const float* __restrict__ W_hh, const float* __restrict__ b_ih,
    const float* __restrict__ b_hh, float* __restrict__ u_out,
    uint* __restrict__ flags, u64* __restrict__ pub) {
  // LDS: [buf 2][b 16][n 512] bf16, byte addr ^ ((b&7)<<4) swizzle. 32 KiB.
  __shared__ uint4 hlds_mem[2048];
  char* hlds = (char*)hlds_mem;

  const int tid = threadIdx.x;
  const int lane = tid & 63;
  const int w = tid >> 6;          // wave 0..3 -> 16-col tile
  const int c = blockIdx.x & 7;    // cohort
  const int i = blockIdx.x >> 3;   // N-slice
  const int l15 = lane & 15;
  const int kg = lane >> 4;        // k-group 0..3 (A) / row-group (C)
  const int n_g = i * 64 + w * 16 + l15;  // this lane's output column

  // ---- one-time: W_hh B-frags for this wave's 16 cols (64 VGPR) ----
  s16x8 wreg[16];
#pragma unroll
  for (int kt = 0; kt < 16; ++kt) {
    const float* wp = W_hh + (size_t)n_g * HH + kt * 32 + kg * 8;
    float4 lo = *(const float4*)wp;
    float4 hi = *(const float4*)(wp + 4);
    s16x8 s;
    s[0] = (short)bf16_rne(lo.x); s[1] = (short)bf16_rne(lo.y);
    s[2] = (short)bf16_rne(lo.z); s[3] = (short)bf16_rne(lo.w);
    s[4] = (short)bf16_rne(hi.x); s[5] = (short)bf16_rne(hi.y);
    s[6] = (short)bf16_rne(hi.z); s[7] = (short)bf16_rne(hi.w);
    wreg[kt] = s;
  }
  const float wih0 = W_ih[n_g * 2 + 0];
  const float wih1 = W_ih[n_g * 2 + 1];
  const float bsum = b_ih[n_g] + b_hh[n_g];

  // ---- zero h buf 0 (h_0 = 0): 16 KB / 256 threads ----
  {
    uint4 z = {0u, 0u, 0u, 0u};
    uint4* p = (uint4*)(hlds + tid * 64);
    p[0] = z; p[1] = z; p[2] = z; p[3] = z;
  }
  __syncthreads();

  const f32x4 z4 = {0.f, 0.f, 0.f, 0.f};
  for (int t = 0; t < TT; ++t) {
    const int cur = t & 1;
    const int nxt = cur ^ 1;

    // vel for this step (L2-resident)
    float2 v[4];
#pragma unroll
    for (int r = 0; r < 4; ++r)
      v[r] = *(const float2*)(vel + ((size_t)(c * 16 + kg * 4 + r) * TT + t) * 2);

    // ---- MFMA: C[16b x 16n] over K=512; 4 chains of depth 4 ----
    f32x4 a0 = z4, a1 = z4, a2 = z4, a3 = z4;
#pragma unroll
    for (int kt = 0; kt < 16; kt += 4) {
      uint base = (uint)cur * 16384u + (uint)l15 * 1024u + (uint)kg * 16u;
      uint swz = ((uint)l15 & 7u) << 4;
      s16x8 f0 = *(const s16x8*)(hlds + ((base + (uint)(kt + 0) * 64u) ^ swz));
      s16x8 f1 = *(const s16x8*)(hlds + ((base + (uint)(kt + 1) * 64u) ^ swz));
      s16x8 f2 = *(const s16x8*)(hlds + ((base + (uint)(kt + 2) * 64u) ^ swz));
      s16x8 f3 = *(const s16x8*)(hlds + ((base + (uint)(kt + 3) * 64u) ^ swz));
      a0 = MFMA_B16(f0, wreg[kt + 0], a0);
      a1 = MFMA_B16(f1, wreg[kt + 1], a1);
      a2 = MFMA_B16(f2, wreg[kt + 2], a2);
      a3 = MFMA_B16(f3, wreg[kt + 3], a3);
    }
    f32x4 acc = (a0 + a1) + (a2 + a3);

    // ---- epilogue: x + tanh (regs only) ----
    float uv[4];
    u64 pk = 0;
#pragma unroll
    for (int r = 0; r < 4; ++r) {
      float x = fmaf(v[r].x, wih0, fmaf(v[r].y, wih1, bsum));
      float uval = tanh_fast(x + acc[r]);
      uv[r] = uval;
      pk |= (u64)bf16_rne(uval) << (16 * r);
    }

    if (t == TT - 1) {
#pragma unroll
      for (int r = 0; r < 4; ++r)
        __builtin_nontemporal_store(
            uv[r], u_out + ((size_t)(c * 16 + kg * 4 + r) * TT + t) * HH + n_g);
      break;
    }

    const int par = nxt;

    // ---- publish own slice straight from regs (col-major pub block) ----
    // pub block (2 KB): [col 64][row 16] bf16; lane -> col w*16+l15, rows kg*4..+3
    {
      u64* dst = pub + (((size_t)par * 8 + c) * 8 + i) * 256 + (w * 16 + l15) * 4 + kg;
      __hip_atomic_store(dst, pk, __ATOMIC_RELAXED, __HIP_MEMORY_SCOPE_AGENT);
    }
    asm volatile("s_waitcnt vmcnt(0)" ::: "memory");  // pub visible at L3
    if (lane == 0)
      __hip_atomic_store(&flags[(c * 8 + i) * 4 + w], (uint)(t + 1),
                         __ATOMIC_RELAXED, __HIP_MEMORY_SCOPE_AGENT);

    // ---- u stores + own-slice LDS write (off the flag critical path) ----
#pragma unroll
    for (int r = 0; r < 4; ++r) {
      int b = kg * 4 + r;
      __builtin_nontemporal_store(
          uv[r], u_out + ((size_t)(c * 16 + b) * TT + t) * HH + n_g);
      uint logical = (uint)nxt * 16384u + (uint)b * 1024u + (uint)n_g * 2u;
      *(ushort_t*)(hlds + (logical ^ (((uint)b & 7u) << 4))) =
          (ushort_t)(pk >> (16 * r));
    }

    // ---- spin on 7 peers x 4 waves = 28 flags (all waves) ----
    {
      int jj = lane >> 2;
      int j = jj + (jj >= i ? 1 : 0);
      int fw = lane & 3;
      const uint tgt = (uint)(t + 1);
      while (true) {
        uint f = (lane < 28)
                     ? __hip_atomic_load(&flags[(c * 8 + j) * 4 + fw],
                                         __ATOMIC_RELAXED, __HIP_MEMORY_SCOPE_AGENT)
                     : 0xFFFFFFFFu;
        if (__all((int)(f >= tgt))) break;
      }
      asm volatile("" ::: "memory");
    }

    // ---- gather 7 remote slices: 7 u64/lane -> swizzled LDS ----
    {
      const int col = tid >> 2;   // 0..63
      const int rq = tid & 3;     // row-quarter
      u64 g[7];
#pragma unroll
      for (int s7 = 0; s7 < 7; ++s7) {
        int j = s7 + (s7 >= i ? 1 : 0);
        g[s7] = __hip_atomic_load(
            pub + (((size_t)par * 8 + c) * 8 + j) * 256 + col * 4 + rq,
            __ATOMIC_RELAXED, __HIP_MEMORY_SCOPE_AGENT);
      }
#pragma unroll
      for (int s7 = 0; s7 < 7; ++s7) {
        int j = s7 + (s7 >= i ? 1 : 0);
        uint n = (uint)(j * 64 + col);
#pragma unroll
        for (int e = 0; e < 4; ++e) {
          uint b = (uint)(rq * 4 + e);
          uint logical = (uint)nxt * 16384u + b * 1024u + n * 2u;
          *(ushort_t*)(hlds + (logical ^ ((b & 7u) << 4))) =
              (ushort_t)(g[s7] >> (16 * e));
        }
      }
    }
    __syncthreads();  // h_{t+1} assembled for all waves
  }
}

__global__ void init_kernel(uint* flags) {
  __hip_atomic_store(&flags[threadIdx.x], 0u, __ATOMIC_RELAXED,
                     __HIP_MEMORY_SCOPE_AGENT);
}

// pos[b,t,:] = u[b,t,:] @ W_out^T + b_out ; one wave per (b,t) row, BW-bound.
__global__ __launch_bounds__(256) void pos_kernel(const float* __restrict__ u,
                                                  const float* __restrict__ W_out,
                                                  const float* __restrict__ b_out,
                                                  float* __restrict__ pos) {
  int row = blockIdx.x * 4 + (threadIdx.x >> 6);
  int lane = threadIdx.x & 63;
  const float* ur = u + (size_t)row * HH + lane * 8;
  float4 u0 = *(const float4*)ur;
  float4 u1 = *(const float4*)(ur + 4);
  float4 w00 = *(const float4*)(W_out + lane * 8);
  float4 w01 = *(const float4*)(W_out + lane * 8 + 4);
  float4 w10 = *(const float4*)(W_out + HH + lane * 8);
  float4 w11 = *(const float4*)(W_out + HH + lane * 8 + 4);
  float p0 = u0.x * w00.x + u0.y * w00.y + u0.z * w00.z + u0.w * w00.w +
             u1.x * w01.x + u1.y * w01.y + u1.z * w01.z + u1.w * w01.w;
  float p1 = u0.x * w10.x + u0.y * w10.y + u0.z * w10.z + u0.w * w10.w +
             u1.x * w11.x + u1.y * w11.y + u1.z * w11.z + u1.w * w11.w;
#pragma unroll
  for (int off = 32; off; off >>= 1) {
    p0 += __shfl_xor(p0, off);
    p1 += __shfl_xor(p1, off);
  }
  if (lane == 0) {
    pos[(size_t)row * 2 + 0] = p0 + b_out[0];
    pos[(size_t)row * 2 + 1] = p1 + b_out[1];
  }
}

extern "C" void kernel_launch(void* const* d_in, const int* in_sizes, int n_in,
                              void* d_out, int out_size, void* d_ws, size_t ws_size,
                              hipStream_t stream) {
  const float* vel   = (const float*)d_in[0];
  const float* W_ih  = (const float*)d_in[1];
  const float* W_hh  = (const float*)d_in[2];
  const float* b_ih  = (const float*)d_in[3];
  const float* b_hh  = (const float*)d_in[4];
  const float* W_out = (const float*)d_in[5];
  const float* b_out = (const float*)d_in[6];

  float* pos = (float*)d_out;              // [B,T,2]
  float* u   = pos + (size_t)BB * TT * 2;  // [B,T,H]

  // ws: flags (256 u32 @ 0, monotonic, re-zeroed each launch) + pub
  // (2 par x 8 cohorts x 8 slices x 2 KB = 256 KB @ +4 KB).
  uint* flags = (uint*)d_ws;
  u64* pub = (u64*)((char*)d_ws + 4096);

  init_kernel<<<1, 256, 0, stream>>>(flags);
  rnn_kernel<<<64, 256, 0, stream>>>(vel, W_ih, W_hh, b_ih, b_hh, u, flags, pub);
  pos_kernel<<<(BB * TT) / 4, 256, 0, stream>>>(u, W_out, b_out, pos);
}

// Round 4
// 2244.510 us; speedup vs baseline: 3.7490x; 1.0045x over previous
//
#include <hip/hip_runtime.h>
#include <hip/hip_bf16.h>

// PathRNN: h_{t+1} = tanh(x_t + W_hh h_t), u = h, pos = u @ W_out^T
// B=128, T=1024, H=512.
// 32 WGs = 8 cohorts (16 batches) x 4 N-slices (128 cols); 4 waves/WG (32 cols each).
// W in regs (128 VGPR/lane). h in 2x16KB swizzled LDS. Exchange via SELF-TAGGED
// u64 words (2 adjacent-col bf16 + 32-bit step tag) through L3 with relaxed
// agent atomics: no fences, no vmcnt drain, no flags. Consumer polls the data.
// 2-parity pub buffers; publish happens only after the step's gather completed,
// which makes overwrite-before-read impossible. Tags zeroed each launch.

#define TT 1024
#define BB 128
#define HH 512

typedef short s16x8 __attribute__((ext_vector_type(8)));
typedef float f32x4 __attribute__((ext_vector_type(4)));
typedef unsigned int uint;
typedef unsigned short ushort_t;
typedef unsigned long long u64;

#define MFMA_B16(a, b, c) __builtin_amdgcn_mfma_f32_16x16x32_bf16((a), (b), (c), 0, 0, 0)
#define ALD(p) __hip_atomic_load((p), __ATOMIC_RELAXED, __HIP_MEMORY_SCOPE_AGENT)
#define AST(p, v) __hip_atomic_store((p), (v), __ATOMIC_RELAXED, __HIP_MEMORY_SCOPE_AGENT)

static __device__ __forceinline__ ushort_t bf16_rne(float f) {
  uint u = __float_as_uint(f);
  u += 0x7fffu + ((u >> 16) & 1u);
  return (ushort_t)(u >> 16);
}

static __device__ __forceinline__ float tanh_fast(float z) {
  float e = __expf(2.0f * z);
  return 1.0f - 2.0f * __builtin_amdgcn_rcpf(e + 1.0f);
}

static __device__ __forceinline__ s16x8 packW(const float* wp) {
  float4 lo = *(const float4*)wp;
  float4 hi = *(const float4*)(wp + 4);
  s16x8 s;
  s[0] = (short)bf16_rne(lo.x); s[1] = (short)bf16_rne(lo.y);
  s[2] = (short)bf16_rne(lo.z); s[3] = (short)bf16_rne(lo.w);
  s[4] = (short)bf16_rne(hi.x); s[5] = (short)bf16_rne(hi.y);
  s[6] = (short)bf16_rne(hi.z); s[7] = (short)bf16_rne(hi.w);
  return s;
}

__global__ __launch_bounds__(256) void rnn_kernel(
    const float* __restrict__ vel, const float* __restrict__ W_ih,
    const float* __restrict__ W_hh, const float* __restrict__ b_ih,
    const float* __restrict__ b_hh, float* __restrict__ u_out,
    u64* __restrict__ pub) {
  // LDS: [buf 2][row 16][col 512] bf16, byte ^ ((row&7)<<4) swizzle. 32 KiB.
  __shared__ uint4 hlds_mem[2048];
  char* hlds = (char*)hlds_mem;

  const int tid = threadIdx.x;
  const int lane = tid & 63;
  const int w = tid >> 6;         // wave 0..3 -> 32-col tile
  const int c = blockIdx.x & 7;   // cohort (bid&7 -> same XCD heuristic)
  const int p = blockIdx.x >> 3;  // N-slice 0..3 (128 cols)
  const int l15 = lane & 15;
  const int kg = lane >> 4;
  const int n0 = p * 128 + w * 32;
  const uint swz = ((uint)l15 & 7u) << 4;

  // ---- one-time: W_hh B-frags, local-K first then remote-K (wrapped order) ----
  s16x8 wl[2][4], wr[2][12];
#pragma unroll
  for (int nt = 0; nt < 2; ++nt) {
    const float* wb = W_hh + (size_t)(n0 + nt * 16 + l15) * HH + kg * 8;
#pragma unroll
    for (int kk = 0; kk < 4; ++kk)
      wl[nt][kk] = packW(wb + (p * 4 + kk) * 32);
#pragma unroll
    for (int j = 0; j < 12; ++j)
      wr[nt][j] = packW(wb + (((p * 4 + 4 + j) & 15)) * 32);
  }
  float wih0[2], wih1[2], bs[2];
#pragma unroll
  for (int nt = 0; nt < 2; ++nt) {
    int n = n0 + nt * 16 + l15;
    wih0[nt] = W_ih[n * 2 + 0];
    wih1[nt] = W_ih[n * 2 + 1];
    bs[nt] = b_ih[n] + b_hh[n];
  }

  // ---- zero h buf 0 (h_0 = 0): 16 KB / 256 threads ----
  {
    uint4 z = {0u, 0u, 0u, 0u};
    uint4* zp = (uint4*)(hlds + tid * 64);
    zp[0] = z; zp[1] = z; zp[2] = z; zp[3] = z;
  }
  __syncthreads();

  const f32x4 z4 = {0.f, 0.f, 0.f, 0.f};
  const int ps0 = (p + 1) & 3, ps1 = (p + 2) & 3, ps2 = (p + 3) & 3;
  const uint remoff = (uint)(p * 256 + 256);  // remote kt byte base (mod 1024)

  for (int t = 0; t < TT; ++t) {
    const int cur = t & 1;
    const int nxt = cur ^ 1;

    // ---- prefetch 12 tagged gather words (3 peers x 4 consecutive) ----
    u64 g00 = 0, g01 = 0, g02 = 0, g03 = 0;
    u64 g10 = 0, g11 = 0, g12 = 0, g13 = 0;
    u64 g20 = 0, g21 = 0, g22 = 0, g23 = 0;
    const u64* sp0 = pub + ((size_t)(cur * 8 + c) * 4 + ps0) * 1024 + tid * 4;
    const u64* sp1 = pub + ((size_t)(cur * 8 + c) * 4 + ps1) * 1024 + tid * 4;
    const u64* sp2 = pub + ((size_t)(cur * 8 + c) * 4 + ps2) * 1024 + tid * 4;
    if (t > 0) {
      g00 = ALD(sp0); g01 = ALD(sp0 + 1); g02 = ALD(sp0 + 2); g03 = ALD(sp0 + 3);
      g10 = ALD(sp1); g11 = ALD(sp1 + 1); g12 = ALD(sp1 + 2); g13 = ALD(sp1 + 3);
      g20 = ALD(sp2); g21 = ALD(sp2 + 1); g22 = ALD(sp2 + 2); g23 = ALD(sp2 + 3);
      asm volatile("" ::: "memory");
    }

    // vel for this step
    float2 v[4];
#pragma unroll
    for (int r = 0; r < 4; ++r)
      v[r] = *(const float2*)(vel + ((size_t)(c * 16 + kg * 4 + r) * TT + t) * 2);

    // ---- local-K MFMAs (own 128 cols of h_t) overlap gather flight ----
    f32x4 a00 = z4, a01 = z4, a10 = z4, a11 = z4;
    const uint abase = (uint)cur * 16384u + (uint)l15 * 1024u + (uint)kg * 16u;
#pragma unroll
    for (int kk = 0; kk < 4; ++kk) {
      s16x8 f = *(const s16x8*)(hlds + ((abase + (uint)(p * 256 + kk * 64)) ^ swz));
      if (kk & 1) { a01 = MFMA_B16(f, wl[0][kk], a01); a11 = MFMA_B16(f, wl[1][kk], a11); }
      else        { a00 = MFMA_B16(f, wl[0][kk], a00); a10 = MFMA_B16(f, wl[1][kk], a10); }
    }

    if (t > 0) {
      const uint tgt = (uint)t;
      const uint grow = (uint)tid >> 4;          // gather row 0..15
      const uint gb = ((uint)cur * 16384u + grow * 1024u + (((uint)tid << 2) & 63u) * 4u) ^
                      ((grow & 7u) << 4);
      // peer 0
      while (true) {
        uint mn = min(min((uint)(g00 >> 32), (uint)(g01 >> 32)),
                      min((uint)(g02 >> 32), (uint)(g03 >> 32)));
        if (mn >= tgt) break;
        g00 = ALD(sp0); g01 = ALD(sp0 + 1); g02 = ALD(sp0 + 2); g03 = ALD(sp0 + 3);
      }
      { uint4 d = {(uint)g00, (uint)g01, (uint)g02, (uint)g03};
        *(uint4*)(hlds + (gb ^ ((uint)ps0 * 256u))) = d; }
      // peer 1
      while (true) {
        uint mn = min(min((uint)(g10 >> 32), (uint)(g11 >> 32)),
                      min((uint)(g12 >> 32), (uint)(g13 >> 32)));
        if (mn >= tgt) break;
        g10 = ALD(sp1); g11 = ALD(sp1 + 1); g12 = ALD(sp1 + 2); g13 = ALD(sp1 + 3);
      }
      { uint4 d = {(uint)g10, (uint)g11, (uint)g12, (uint)g13};
        *(uint4*)(hlds + (gb ^ ((uint)ps1 * 256u))) = d; }
      // peer 2
      while (true) {
        uint mn = min(min((uint)(g20 >> 32), (uint)(g21 >> 32)),
                      min((uint)(g22 >> 32), (uint)(g23 >> 32)));
        if (mn >= tgt) break;
        g20 = ALD(sp2); g21 = ALD(sp2 + 1); g22 = ALD(sp2 + 2); g23 = ALD(sp2 + 3);
      }
      { uint4 d = {(uint)g20, (uint)g21, (uint)g22, (uint)g23};
        *(uint4*)(hlds + (gb ^ ((uint)ps2 * 256u))) = d; }
      __syncthreads();  // full h_t assembled
    }

    // ---- remote-K MFMAs (wrapped order matches wr[]) ----
#pragma unroll
    for (int j = 0; j < 12; ++j) {
      uint off = (remoff + (uint)(j * 64)) & 1023u;
      s16x8 f = *(const s16x8*)(hlds + ((abase + off) ^ swz));
      if (j & 1) { a01 = MFMA_B16(f, wr[0][j], a01); a11 = MFMA_B16(f, wr[1][j], a11); }
      else       { a00 = MFMA_B16(f, wr[0][j], a00); a10 = MFMA_B16(f, wr[1][j], a10); }
    }
    f32x4 acc0 = a00 + a01;
    f32x4 acc1 = a10 + a11;

    // ---- epilogue: x + tanh ----
    float uv0[4], uv1[4];
    ushort_t hb0[4], hb1[4];
#pragma unroll
    for (int r = 0; r < 4; ++r) {
      float x0 = fmaf(v[r].x, wih0[0], fmaf(v[r].y, wih1[0], bs[0]));
      float x1 = fmaf(v[r].x, wih0[1], fmaf(v[r].y, wih1[1], bs[1]));
      uv0[r] = tanh_fast(x0 + acc0[r]);
      uv1[r] = tanh_fast(x1 + acc1[r]);
      hb0[r] = bf16_rne(uv0[r]);
      hb1[r] = bf16_rne(uv1[r]);
    }

    if (t < TT - 1) {
      // ---- col-pair pack via shfl_xor(1); publish tagged words ----
      const bool odd = (l15 & 1) != 0;
      const uint rowbase = (uint)(kg * 4) + (odd ? 2u : 0u);
      const uint cpq = (uint)(w * 16) + ((uint)l15 >> 1);
      u64* dpb = pub + ((size_t)(nxt * 8 + c) * 4 + p) * 1024;
      const u64 tagw = (u64)(uint)(t + 1) << 32;
      const uint ldsb = (uint)nxt * 16384u;
#pragma unroll
      for (int nt = 0; nt < 2; ++nt) {
        const ushort_t* hb = nt ? hb1 : hb0;
        uint a01p = (uint)hb[0] | ((uint)hb[1] << 16);
        uint a23p = (uint)hb[2] | ((uint)hb[3] << 16);
        uint b01p = __shfl_xor(a01p, 1);
        uint b23p = __shfl_xor(a23p, 1);
        uint eP = odd ? b23p : a01p;  // even-col packed rows (rowbase, rowbase+1)
        uint oP = odd ? a23p : b01p;  // odd-col packed
        uint pr0 = (eP & 0xFFFFu) | (oP << 16);
        uint pr1 = (eP >> 16) | (oP & 0xFFFF0000u);
        uint cp = cpq + (uint)(nt * 8);
        AST(dpb + rowbase * 64 + cp, (u64)pr0 | tagw);
        AST(dpb + (rowbase + 1) * 64 + cp, (u64)pr1 | tagw);
        // own-slice LDS write (buf nxt), u32 col-pairs
        uint cb = (uint)(n0 + nt * 16 + (l15 & ~1)) * 2u;
        *(uint*)(hlds + ((ldsb + rowbase * 1024u + cb) ^ ((rowbase & 7u) << 4))) = pr0;
        *(uint*)(hlds + ((ldsb + (rowbase + 1) * 1024u + cb) ^ (((rowbase + 1) & 7u) << 4))) = pr1;
      }
    }

    // ---- u stores (fire-and-forget) ----
#pragma unroll
    for (int r = 0; r < 4; ++r) {
      size_t ub = ((size_t)(c * 16 + kg * 4 + r) * TT + t) * HH;
      __builtin_nontemporal_store(uv0[r], u_out + ub + n0 + l15);
      __builtin_nontemporal_store(uv1[r], u_out + ub + n0 + 16 + l15);
    }

    if (t == TT - 1) break;
    __syncthreads();  // own h_{t+1} slice visible to all waves
  }
}

__global__ void init_kernel(u64* pub) {
  int idx = (blockIdx.x * 256 + threadIdx.x) * 4;
#pragma unroll
  for (int k = 0; k < 4; ++k)
    __hip_atomic_store(&pub[idx + k], 0ull, __ATOMIC_RELAXED, __HIP_MEMORY_SCOPE_AGENT);
}

// pos[b,t,:] = u[b,t,:] @ W_out^T + b_out ; one wave per (b,t) row, BW-bound.
__global__ __launch_bounds__(256) void pos_kernel(const float* __restrict__ u,
                                                  const float* __restrict__ W_out,
                                                  const float* __restrict__ b_out,
                                                  float* __restrict__ pos) {
  int row = blockIdx.x * 4 + (threadIdx.x >> 6);
  int lane = threadIdx.x & 63;
  const float* ur = u + (size_t)row * HH + lane * 8;
  float4 u0 = *(const float4*)ur;
  float4 u1 = *(const float4*)(ur + 4);
  float4 w00 = *(const float4*)(W_out + lane * 8);
  float4 w01 = *(const float4*)(W_out + lane * 8 + 4);
  float4 w10 = *(const float4*)(W_out + HH + lane * 8);
  float4 w11 = *(const float4*)(W_out + HH + lane * 8 + 4);
  float p0 = u0.x * w00.x + u0.y * w00.y + u0.z * w00.z + u0.w * w00.w +
             u1.x * w01.x + u1.y * w01.y + u1.z * w01.z + u1.w * w01.w;
  float p1 = u0.x * w10.x + u0.y * w10.y + u0.z * w10.z + u0.w * w10.w +
             u1.x * w11.x + u1.y * w11.y + u1.z * w11.z + u1.w * w11.w;
#pragma unroll
  for (int off = 32; off; off >>= 1) {
    p0 += __shfl_xor(p0, off);
    p1 += __shfl_xor(p1, off);
  }
  if (lane == 0) {
    pos[(size_t)row * 2 + 0] = p0 + b_out[0];
    pos[(size_t)row * 2 + 1] = p1 + b_out[1];
  }
}

extern "C" void kernel_launch(void* const* d_in, const int* in_sizes, int n_in,
                              void* d_out, int out_size, void* d_ws, size_t ws_size,
                              hipStream_t stream) {
  const float* vel   = (const float*)d_in[0];
  const float* W_ih  = (const float*)d_in[1];
  const float* W_hh  = (const float*)d_in[2];
  const float* b_ih  = (const float*)d_in[3];
  const float* b_hh  = (const float*)d_in[4];
  const float* W_out = (const float*)d_in[5];
  const float* b_out = (const float*)d_in[6];

  float* pos = (float*)d_out;              // [B,T,2]
  float* u   = pos + (size_t)BB * TT * 2;  // [B,T,H]

  // ws: pub = 2 parities x 8 cohorts x 4 slices x 1024 u64 = 512 KB of tagged words
  u64* pub = (u64*)d_ws;

  init_kernel<<<64, 256, 0, stream>>>(pub);  // zero all tags (replay determinism)
  rnn_kernel<<<32, 256, 0, stream>>>(vel, W_ih, W_hh, b_ih, b_hh, u, pub);
  pos_kernel<<<(BB * TT) / 4, 256, 0, stream>>>(u, W_out, b_out, pos);
}